// Round 1
// baseline (192.983 us; speedup 1.0000x reference)
//
#include <hip/hip_runtime.h>
#include <hip/hip_bf16.h>

// LocalAttention: B=8, S=4096, D=512, H=8, hd=64, WINDOW=5, STRIDE=4, nw=1024
// Decomposition: QKV proj per-position (GEMM) -> per-window 5x5 attention ->
// overlap-summed attn-out -> output GEMM with count-scaling -> attn mean reduce.

#define SEQ   4096
#define NB    8
#define DIM   512
#define NWIN  1024
#define MTOT  (NB*SEQ)   // 32768

typedef __bf16 bf16x8 __attribute__((ext_vector_type(8)));
typedef float  f32x4  __attribute__((ext_vector_type(4)));

__device__ __forceinline__ float b2f(unsigned short u) {
  union { unsigned int i; float f; } z; z.i = ((unsigned int)u) << 16; return z.f;
}
__device__ __forceinline__ unsigned short f2b(float f) {
  __bf16 h = (__bf16)f; return __builtin_bit_cast(unsigned short, h);
}
__device__ __forceinline__ void gload_lds16(const void* g, void* l) {
  __builtin_amdgcn_global_load_lds(
      (__attribute__((address_space(1))) void*)g,
      (__attribute__((address_space(3))) void*)l, 16, 0, 0);
}

// ---------------- convert x (fp32 -> bf16) ----------------
__global__ __launch_bounds__(256) void cvt_x(const float* __restrict__ x,
                                             unsigned short* __restrict__ o, int n8) {
  int stride = gridDim.x * blockDim.x;
  for (int i = blockIdx.x * blockDim.x + threadIdx.x; i < n8; i += stride) {
    const float4 a = *(const float4*)(x + (size_t)i * 8);
    const float4 c = *(const float4*)(x + (size_t)i * 8 + 4);
    unsigned short u[8] = {f2b(a.x), f2b(a.y), f2b(a.z), f2b(a.w),
                           f2b(c.x), f2b(c.y), f2b(c.z), f2b(c.w)};
    *(int4*)(o + (size_t)i * 8) = *(const int4*)u;
  }
}

// ---------------- convert+transpose weights: Wt[w][n][k] = bf16(W[k][n]) ----------------
__global__ __launch_bounds__(256) void cvt_w(const float* __restrict__ W0, const float* __restrict__ W1,
                                             const float* __restrict__ W2, const float* __restrict__ W3,
                                             unsigned short* __restrict__ Wt) {
  int i = blockIdx.x * 256 + threadIdx.x;   // 4*512*512 threads
  int w = i >> 18;
  int r = i & 262143;
  int nn = r >> 9, kk = r & 511;
  const float* W = (w == 0) ? W0 : (w == 1) ? W1 : (w == 2) ? W2 : W3;
  Wt[i] = f2b(W[kk * 512 + nn]);
}

// ---------------- QKV GEMM: C = A @ Wt^T + bias (bf16 out) ----------------
// grid (12, 256): blockIdx.x>>2 selects {Q,K,V}, (blockIdx.x&3)*128 = n0
__global__ __launch_bounds__(256) void gemm_qkv(
    const unsigned short* __restrict__ A, const unsigned short* __restrict__ Wt,
    const float* __restrict__ bq, const float* __restrict__ bk, const float* __restrict__ bv,
    unsigned short* __restrict__ Qb, unsigned short* __restrict__ Kb, unsigned short* __restrict__ Vb) {
  __shared__ unsigned short As[128 * 32];
  __shared__ unsigned short Bs[128 * 32];
  const int sel = blockIdx.x >> 2;
  const int n0 = (blockIdx.x & 3) * 128;
  const int m0 = blockIdx.y * 128;
  const unsigned short* Bt = Wt + (size_t)sel * (DIM * DIM);
  const float* bias = (sel == 0) ? bq : (sel == 1) ? bk : bv;
  unsigned short* C = (sel == 0) ? Qb : (sel == 1) ? Kb : Vb;

  const int tid = threadIdx.x;
  const int lane = tid & 63;
  const int wid = tid >> 6;
  const int wr = wid >> 1, wc = wid & 1;

  f32x4 acc[4][4] = {};

  for (int k0 = 0; k0 < DIM; k0 += 32) {
#pragma unroll
    for (int it = 0; it < 2; ++it) {
      int c = it * 256 + tid;
      int row = c >> 2, kk = (c & 3) << 3;
      gload_lds16(A + (size_t)(m0 + row) * DIM + k0 + kk, &As[(it * 256 + wid * 64) * 8]);
      gload_lds16(Bt + (size_t)(n0 + row) * DIM + k0 + kk, &Bs[(it * 256 + wid * 64) * 8]);
    }
    __syncthreads();
    bf16x8 af[4], bfr[4];
#pragma unroll
    for (int m = 0; m < 4; ++m) {
      int r = wr * 64 + m * 16 + (lane & 15);
      af[m] = __builtin_bit_cast(bf16x8, *(const int4*)&As[r * 32 + ((lane >> 4) << 3)]);
    }
#pragma unroll
    for (int n = 0; n < 4; ++n) {
      int r = wc * 64 + n * 16 + (lane & 15);
      bfr[n] = __builtin_bit_cast(bf16x8, *(const int4*)&Bs[r * 32 + ((lane >> 4) << 3)]);
    }
#pragma unroll
    for (int m = 0; m < 4; ++m)
#pragma unroll
      for (int n = 0; n < 4; ++n)
        acc[m][n] = __builtin_amdgcn_mfma_f32_16x16x32_bf16(af[m], bfr[n], acc[m][n], 0, 0, 0);
    __syncthreads();
  }
  const int cl = lane & 15, rh = lane >> 4;
#pragma unroll
  for (int n = 0; n < 4; ++n) {
    int col = n0 + wc * 64 + n * 16 + cl;
    float bcol = bias[col];
#pragma unroll
    for (int m = 0; m < 4; ++m) {
      int rbase = m0 + wr * 64 + m * 16 + rh * 4;
#pragma unroll
      for (int r = 0; r < 4; ++r)
        C[(size_t)(rbase + r) * DIM + col] = f2b(acc[m][n][r] + bcol);
    }
  }
}

// ---------------- windowed attention ----------------
// one wave per window (4 windows / 256-thread block); 8 lanes per head.
__global__ __launch_bounds__(256) void attn_win(
    const unsigned short* __restrict__ Qb, const unsigned short* __restrict__ Kb,
    const unsigned short* __restrict__ Vb,
    const float* __restrict__ bq, const float* __restrict__ bk, const float* __restrict__ bv,
    unsigned short* __restrict__ yb, unsigned short* __restrict__ yext,
    float* __restrict__ abuf) {
  const int gw = blockIdx.x * 4 + (threadIdx.x >> 6);
  const int b = gw >> 10, n = gw & (NWIN - 1);
  const int lane = threadIdx.x & 63;
  const int h = lane >> 3, e = lane & 7;
  const int dbase = h * 64 + e * 8;

  float kf[5][8], vf[5][8];
#pragma unroll
  for (int j = 0; j < 5; ++j) {
    int p = 4 * n + j;
    if (p < SEQ) {
      int4 kv = *(const int4*)(Kb + ((size_t)b * SEQ + p) * DIM + dbase);
      int4 vv = *(const int4*)(Vb + ((size_t)b * SEQ + p) * DIM + dbase);
      const unsigned short* kp = (const unsigned short*)&kv;
      const unsigned short* vp = (const unsigned short*)&vv;
#pragma unroll
      for (int d = 0; d < 8; ++d) { kf[j][d] = b2f(kp[d]); vf[j][d] = b2f(vp[d]); }
    } else {  // zero-pad row: k = bk, v = bv (only window 1023, j=4)
#pragma unroll
      for (int d = 0; d < 8; ++d) { kf[j][d] = bk[dbase + d]; vf[j][d] = bv[dbase + d]; }
    }
  }
  float pm[5][5];
#pragma unroll
  for (int i = 0; i < 5; ++i) {
    int p = 4 * n + i;
    float qf[8];
    if (p < SEQ) {
      int4 qv = *(const int4*)(Qb + ((size_t)b * SEQ + p) * DIM + dbase);
      const unsigned short* qp = (const unsigned short*)&qv;
#pragma unroll
      for (int d = 0; d < 8; ++d) qf[d] = b2f(qp[d]);
    } else {
#pragma unroll
      for (int d = 0; d < 8; ++d) qf[d] = bq[dbase + d];
    }
    float sr[5];
#pragma unroll
    for (int j = 0; j < 5; ++j) {
      float t = 0.f;
#pragma unroll
      for (int d = 0; d < 8; ++d) t += qf[d] * kf[j][d];
      t += __shfl_xor(t, 1);
      t += __shfl_xor(t, 2);
      t += __shfl_xor(t, 4);
      sr[j] = t * 0.125f;   // 1/sqrt(64)
    }
    float mx = sr[0];
#pragma unroll
    for (int j = 1; j < 5; ++j) mx = fmaxf(mx, sr[j]);
    float ex[5], sum = 0.f;
#pragma unroll
    for (int j = 0; j < 5; ++j) { ex[j] = expf(sr[j] - mx); sum += ex[j]; }
    float inv = 1.0f / sum;
#pragma unroll
    for (int j = 0; j < 5; ++j) pm[i][j] = ex[j] * inv;
    float o[8];
#pragma unroll
    for (int d = 0; d < 8; ++d) o[d] = 0.f;
#pragma unroll
    for (int j = 0; j < 5; ++j)
#pragma unroll
      for (int d = 0; d < 8; ++d) o[d] += pm[i][j] * vf[j][d];
    unsigned short u[8];
#pragma unroll
    for (int d = 0; d < 8; ++d) u[d] = f2b(o[d]);
    if (i < 4) {  // positions 4n+0..3 are uniquely owned -> plain store
      *(int4*)(yb + ((size_t)b * SEQ + p) * DIM + dbase) = *(const int4*)u;
    } else {      // w=4 contribution for position 4(n+1) -> side buffer
      *(int4*)(yext + ((size_t)b * NWIN + n) * DIM + dbase) = *(const int4*)u;
    }
  }
  // per-window attn probabilities (for attn_weights mean); static indices only
  float* ap = abuf + ((size_t)(b * NWIN + n) * 8 + h) * 25;
  if (e == 0) {
#pragma unroll
    for (int i2 = 0; i2 < 5; ++i2)
#pragma unroll
      for (int j2 = 0; j2 < 5; ++j2) ap[i2 * 5 + j2] = pm[i2][j2];
  }
}

// ---------------- final GEMM: out = (y_sum @ Wo + cnt*bo) / (cnt + 1e-6) ----------------
__global__ __launch_bounds__(256) void gemm_final(
    const unsigned short* __restrict__ Yb, const unsigned short* __restrict__ Yext,
    const unsigned short* __restrict__ Bt, const float* __restrict__ bo,
    float* __restrict__ Cout) {
  __shared__ unsigned short As[128 * 32];
  __shared__ unsigned short Bs[128 * 32];
  const int n0 = blockIdx.x * 128;
  const int m0 = blockIdx.y * 128;
  const int tid = threadIdx.x;
  const int lane = tid & 63;
  const int wid = tid >> 6;
  const int wr = wid >> 1, wc = wid & 1;

  f32x4 acc[4][4] = {};

  for (int k0 = 0; k0 < DIM; k0 += 32) {
#pragma unroll
    for (int it = 0; it < 2; ++it) {
      int c = it * 256 + tid;
      int row = c >> 2, kk = (c & 3) << 3;
      gload_lds16(Bt + (size_t)(n0 + row) * DIM + k0 + kk, &Bs[(it * 256 + wid * 64) * 8]);
      int gr = m0 + row;
      int s = gr & (SEQ - 1);
      int4 v = *(const int4*)(Yb + (size_t)gr * DIM + k0 + kk);
      if ((s & 3) == 0 && s > 0) {  // overlap position: add previous window's w=4 row
        int b = gr >> 12;
        int4 ev = *(const int4*)(Yext + ((size_t)b * NWIN + (s >> 2) - 1) * DIM + k0 + kk);
        unsigned short* pv = (unsigned short*)&v;
        const unsigned short* pe = (const unsigned short*)&ev;
#pragma unroll
        for (int j = 0; j < 8; ++j) pv[j] = f2b(b2f(pv[j]) + b2f(pe[j]));
      }
      *(int4*)&As[c * 8] = v;
    }
    __syncthreads();
    bf16x8 af[4], bfr[4];
#pragma unroll
    for (int m = 0; m < 4; ++m) {
      int r = wr * 64 + m * 16 + (lane & 15);
      af[m] = __builtin_bit_cast(bf16x8, *(const int4*)&As[r * 32 + ((lane >> 4) << 3)]);
    }
#pragma unroll
    for (int n = 0; n < 4; ++n) {
      int r = wc * 64 + n * 16 + (lane & 15);
      bfr[n] = __builtin_bit_cast(bf16x8, *(const int4*)&Bs[r * 32 + ((lane >> 4) << 3)]);
    }
#pragma unroll
    for (int m = 0; m < 4; ++m)
#pragma unroll
      for (int n = 0; n < 4; ++n)
        acc[m][n] = __builtin_amdgcn_mfma_f32_16x16x32_bf16(af[m], bfr[n], acc[m][n], 0, 0, 0);
    __syncthreads();
  }
  const int cl = lane & 15, rh = lane >> 4;
#pragma unroll
  for (int n = 0; n < 4; ++n) {
    int col = n0 + wc * 64 + n * 16 + cl;
    float bcol = bo[col];
#pragma unroll
    for (int m = 0; m < 4; ++m) {
      int rbase = m0 + wr * 64 + m * 16 + rh * 4;
#pragma unroll
      for (int r = 0; r < 4; ++r) {
        int row = rbase + r;
        int s = row & (SEQ - 1);
        float cnt = ((s & 3) == 0 && s > 0) ? 2.0f : 1.0f;
        Cout[(size_t)row * DIM + col] = (acc[m][n][r] + cnt * bcol) / (cnt + 1e-6f);
      }
    }
  }
}

// ---------------- attn_weights: mean over windows (deterministic tree reduce) ----------------
__global__ __launch_bounds__(256) void attn_reduce(const float* __restrict__ abuf,
                                                   float* __restrict__ out) {
  __shared__ float sm[256][25];
  int bh = blockIdx.x;  // b*8+h
  int b = bh >> 3, h = bh & 7;
  int t = threadIdx.x;
  float loc[25];
#pragma unroll
  for (int j = 0; j < 25; ++j) loc[j] = 0.f;
  for (int n = t; n < NWIN; n += 256) {
    const float* p = abuf + ((size_t)(b * NWIN + n) * 8 + h) * 25;
#pragma unroll
    for (int j = 0; j < 25; ++j) loc[j] += p[j];
  }
#pragma unroll
  for (int j = 0; j < 25; ++j) sm[t][j] = loc[j];
  __syncthreads();
  for (int off = 128; off > 0; off >>= 1) {
    if (t < off)
#pragma unroll
      for (int j = 0; j < 25; ++j) sm[t][j] += sm[t + off][j];
    __syncthreads();
  }
  if (t < 25) out[bh * 25 + t] = sm[0][t] * (1.0f / 1024.0f);
}

extern "C" void kernel_launch(void* const* d_in, const int* in_sizes, int n_in,
                              void* d_out, int out_size, void* d_ws, size_t ws_size,
                              hipStream_t stream) {
  const float* x  = (const float*)d_in[0];
  const float* Wq = (const float*)d_in[1];
  const float* bq = (const float*)d_in[2];
  const float* Wk = (const float*)d_in[3];
  const float* bk = (const float*)d_in[4];
  const float* Wv = (const float*)d_in[5];
  const float* bv = (const float*)d_in[6];
  const float* Wo = (const float*)d_in[7];
  const float* bo = (const float*)d_in[8];
  float* out = (float*)d_out;

  // workspace layout (~144.2 MiB). xb aliases yb (xb dead after gemm_qkv).
  char* ws = (char*)d_ws;
  unsigned short* xb   = (unsigned short*)(ws);              // 32 MiB (bf16 x / later y)
  unsigned short* yb   = xb;                                 // alias
  unsigned short* Qb   = (unsigned short*)(ws + 33554432);   // 32 MiB
  unsigned short* Kb   = (unsigned short*)(ws + 67108864);   // 32 MiB
  unsigned short* Vb   = (unsigned short*)(ws + 100663296);  // 32 MiB
  unsigned short* yext = (unsigned short*)(ws + 134217728);  // 8 MiB
  float*          abuf = (float*)(ws + 142606336);           // 6.25 MiB
  unsigned short* Wt   = (unsigned short*)(ws + 149159936);  // 2 MiB
  (void)ws_size; (void)in_sizes; (void)n_in; (void)out_size;

  cvt_x<<<2048, 256, 0, stream>>>(x, xb, MTOT * DIM / 8);
  cvt_w<<<4096, 256, 0, stream>>>(Wq, Wk, Wv, Wo, Wt);
  gemm_qkv<<<dim3(12, 256), 256, 0, stream>>>(xb, Wt, bq, bk, bv, Qb, Kb, Vb);
  attn_win<<<2048, 256, 0, stream>>>(Qb, Kb, Vb, bq, bk, bv, yb, yext, abuf);
  gemm_final<<<dim3(4, 256), 256, 0, stream>>>(yb, yext, Wt + 3 * (DIM * DIM), bo, out);
  attn_reduce<<<64, 256, 0, stream>>>(abuf, out + (size_t)MTOT * DIM);
}